// Round 1
// baseline (3290.768 us; speedup 1.0000x reference)
//
#include <hip/hip_runtime.h>

#define LF 8192
#define NB 8
#define NC 512
#define NA 7
#define NANCH 57344        // LF*NA
#define PRE_K 600
#define POST_K 100

// output layout (floats), concatenated in reference return order
#define OBJ_OFF   0
#define REG_OFF   458752
#define ANCH_OFF  1376256
#define PROPS_OFF 1490944
#define PSC_OFF   1492544
#define PM_OFF    1493344

// ---------------- weight transpose: conv_w[co][ci][k] -> wt[(ci*3+k)*512+co] ----
__global__ void transpose_w_k(const float* __restrict__ cw, float* __restrict__ wt) {
  int o = blockIdx.x * 256 + threadIdx.x;
  if (o >= 512 * 512 * 3) return;
  int co = o & 511;
  int r  = o >> 9;            // ci*3 + k
  int ci = r / 3;
  int k  = r - ci * 3;
  wt[o] = cw[((size_t)co * 512 + ci) * 3 + k];
}

// ---------------- anchors ------------------------------------------------------
__global__ void anchors_k(float* __restrict__ out) {
  int i = blockIdx.x * 256 + threadIdx.x;
  if (i >= NANCH) return;
  int l = i / 7, a = i - l * 7;
  float len = (float)(a + 1 + (a > 4 ? a - 4 : 0));   // {1,2,3,4,5,7,9}
  float c = (float)l + 0.5f;
  out[ANCH_OFF + 2 * (size_t)i]     = c - 0.5f * len;
  out[ANCH_OFF + 2 * (size_t)i + 1] = c + 0.5f * len;
}

// ---------------- fused conv1d + ReLU + obj/reg projection ---------------------
// grid (LF/64, B), block 256. Each WG: l-tile of 64, full 512 c_out in 4
// quarter passes (wave w handles 32 c_out per quarter; lane = l). Weights via
// wave-uniform scalar loads from transposed wt; feat staged in LDS.
__global__ __launch_bounds__(256, 2) void conv_proj_k(
    const float* __restrict__ feat, const float* __restrict__ wt,
    const float* __restrict__ cbias, const float* __restrict__ obj_w,
    const float* __restrict__ obj_b, const float* __restrict__ reg_w,
    const float* __restrict__ reg_b, float* __restrict__ out)
{
  __shared__ float sh[128 * 64];   // relu(h) quarter tile [co_local][l]
  __shared__ float sf[32][66];     // feat tile [ci][l0-1 .. l0+64]
  const int tid  = threadIdx.x;
  const int lane = tid & 63;
  const int wv   = __builtin_amdgcn_readfirstlane(tid >> 6);
  const int l0 = blockIdx.x * 64;
  const int b  = blockIdx.y;
  const int l  = l0 + lane;

  float pacc[6] = {0.f, 0.f, 0.f, 0.f, 0.f, 0.f};   // projection rows r = wv + 4q

  for (int qh = 0; qh < 4; ++qh) {
    const int co_u = __builtin_amdgcn_readfirstlane(qh * 128 + wv * 32);
    float acc[32];
    #pragma unroll
    for (int j = 0; j < 32; ++j) acc[j] = cbias[co_u + j];

    for (int cb = 0; cb < 512; cb += 32) {
      __syncthreads();
      for (int idx = tid; idx < 32 * 66; idx += 256) {
        int r = idx / 66, c = idx - r * 66;
        int gl = l0 - 1 + c;
        float v = 0.f;
        if (gl >= 0 && gl < LF) v = feat[((size_t)(b * 512 + cb + r) << 13) + gl];
        sf[r][c] = v;
      }
      __syncthreads();
      for (int ci = 0; ci < 32; ++ci) {
        float f0 = sf[ci][lane];
        float f1 = sf[ci][lane + 1];
        float f2 = sf[ci][lane + 2];
        const float* w0 = wt + (size_t)(cb + ci) * 3 * 512 + co_u;
        const float* w1 = w0 + 512;
        const float* w2 = w0 + 1024;
        #pragma unroll
        for (int j = 0; j < 32; ++j) acc[j] = fmaf(w0[j], f0, acc[j]);
        #pragma unroll
        for (int j = 0; j < 32; ++j) acc[j] = fmaf(w1[j], f1, acc[j]);
        #pragma unroll
        for (int j = 0; j < 32; ++j) acc[j] = fmaf(w2[j], f2, acc[j]);
      }
    }
    // write relu(h) quarter to LDS
    #pragma unroll
    for (int j = 0; j < 32; ++j)
      sh[(wv * 32 + j) * 64 + lane] = fmaxf(acc[j], 0.f);
    __syncthreads();
    // partial projection over this quarter's 128 channels
    for (int c = 0; c < 128; ++c) {
      float hv = sh[c * 64 + lane];
      int cg = qh * 128 + c;
      #pragma unroll
      for (int q = 0; q < 6; ++q) {
        int r = wv + 4 * q;
        if (r < 21) {
          const float* wr = (r < 7) ? (obj_w + (size_t)r * 512)
                                    : (reg_w + (size_t)(r - 7) * 512);
          pacc[q] = fmaf(wr[cg], hv, pacc[q]);
        }
      }
    }
    __syncthreads();   // protect sh/sf before next quarter
  }

  const size_t ob = (size_t)b * NANCH;
  #pragma unroll
  for (int q = 0; q < 6; ++q) {
    int r = wv + 4 * q;
    if (r < 21) {
      float v = pacc[q] + ((r < 7) ? obj_b[r] : reg_b[r - 7]);
      if (r < 7) {
        out[OBJ_OFF + ob + (size_t)l * 7 + r] = v;
      } else {
        int rr = r - 7;
        out[REG_OFF + (ob + (size_t)l * 7 + (rr >> 1)) * 2 + (rr & 1)] = v;
      }
    }
  }
}

// ---------------- helper: locate bin containing rank-K from top ----------------
__device__ __forceinline__ void find_bin(unsigned* hist, unsigned* coarse,
                                         int K, int tid, int* res) {
  unsigned s4 = hist[4 * tid] + hist[4 * tid + 1] + hist[4 * tid + 2] + hist[4 * tid + 3];
  coarse[tid] = s4;
  __syncthreads();
  for (int off = 1; off < 256; off <<= 1) {
    unsigned v = coarse[tid];
    unsigned add = (tid + off < 256) ? coarse[tid + off] : 0u;
    __syncthreads();
    coarse[tid] = v + add;
    __syncthreads();
  }
  unsigned sfx  = coarse[tid];
  unsigned sfx1 = (tid < 255) ? coarse[tid + 1] : 0u;
  if (sfx >= (unsigned)K && sfx1 < (unsigned)K) {
    unsigned above = sfx1;
    int bin = 4 * tid;
    for (int bb = 4 * tid + 3; bb >= 4 * tid; --bb) {
      unsigned c = hist[bb];
      if (above + c >= (unsigned)K) { bin = bb; break; }
      above += c;
    }
    res[0] = bin;
    res[1] = (int)above;
  }
  __syncthreads();
}

// ---------------- per-batch top-600 -> NMS -> top-100 --------------------------
__global__ __launch_bounds__(256) void propose_k(float* __restrict__ out) {
  const int b = blockIdx.x;
  const int tid = threadIdx.x;
  const int lane = tid & 63;
  const int wave = tid >> 6;

  __shared__ unsigned long long pool[PRE_K * 10];  // 48 KB; first 1024 = sort keys
  __shared__ unsigned int hist[1024];
  __shared__ unsigned int coarse[256];
  __shared__ float bs[PRE_K], be[PRE_K], bsc[PRE_K];
  __shared__ unsigned long long vwords[10];
  __shared__ int scal[4];   // 0: bin, 1: before, 2: cand cnt, 3: kept

  unsigned long long* keys = pool;
  const float* obj = out + OBJ_OFF + (size_t)b * NANCH;

  for (int i = tid; i < 1024; i += 256) hist[i] = 0u;
  if (tid < 10) vwords[tid] = 0ull;
  if (tid == 0) scal[2] = 0;
  __syncthreads();

  // pass 1: histogram on score bits [31:22] (scores positive -> bit order = value order)
  for (int i = tid; i < NANCH; i += 256) {
    float s = 1.f / (1.f + expf(-obj[i]));
    unsigned u = __float_as_uint(s);
    atomicAdd(&hist[u >> 22], 1u);
  }
  __syncthreads();
  find_bin(hist, coarse, PRE_K, tid, scal);
  const int b1 = scal[0];
  const int before = scal[1];
  __syncthreads();
  for (int i = tid; i < 1024; i += 256) hist[i] = 0u;
  __syncthreads();
  // pass 2: refine next 10 bits within bin b1
  for (int i = tid; i < NANCH; i += 256) {
    float s = 1.f / (1.f + expf(-obj[i]));
    unsigned u = __float_as_uint(s);
    if ((int)(u >> 22) == b1) atomicAdd(&hist[(u >> 12) & 1023u], 1u);
  }
  __syncthreads();
  find_bin(hist, coarse, PRE_K - before, tid, scal);
  const unsigned Tbits = ((unsigned)b1 << 22) | ((unsigned)scal[0] << 12);
  __syncthreads();
  // gather candidates (>=600 guaranteed, ~600 expected)
  for (int i = tid; i < NANCH; i += 256) {
    float s = 1.f / (1.f + expf(-obj[i]));
    unsigned u = __float_as_uint(s);
    if (u >= Tbits) {
      int p = atomicAdd(&scal[2], 1);
      if (p < 1024)
        keys[p] = ((unsigned long long)u << 32) | (unsigned long long)(~(unsigned)i);
    }
  }
  __syncthreads();
  const int cnt = scal[2];
  for (int p = tid; p < 1024; p += 256) if (p >= cnt) keys[p] = 0ull;
  // bitonic sort descending (key: score bits major, ~idx minor -> ties by lower idx)
  for (unsigned k = 2; k <= 1024; k <<= 1) {
    for (unsigned j = k >> 1; j > 0; j >>= 1) {
      __syncthreads();
      for (unsigned idx = tid; idx < 1024; idx += 256) {
        unsigned partner = idx ^ j;
        if (partner > idx) {
          unsigned long long a = keys[idx], c = keys[partner];
          bool up = ((idx & k) == 0);
          if (up ? (a < c) : (a > c)) { keys[idx] = c; keys[partner] = a; }
        }
      }
    }
  }
  __syncthreads();
  // decode top-600 boxes
  for (int t = tid; t < PRE_K; t += 256) {
    unsigned long long kv = keys[t];
    unsigned u  = (unsigned)(kv >> 32);
    unsigned i2 = ~((unsigned)kv);
    float score = __uint_as_float(u);
    int li = (int)(i2 / 7u);
    int a  = (int)(i2 - (unsigned)li * 7u);
    float alen = (float)(a + 1 + (a > 4 ? a - 4 : 0));
    const float* rp = out + REG_OFF + ((size_t)b * NANCH + i2) * 2;
    float tc = rp[0];
    float tw = fminf(fmaxf(rp[1], -10.f), 10.f);
    float cc = (float)li + 0.5f + tc * alen;
    float ww = alen * expf(tw);
    float s0 = cc - 0.5f * ww;
    float e0 = cc + 0.5f * ww;
    s0 = fminf(fmaxf(s0, 0.f), (float)LF);
    e0 = fminf(fmaxf(e0, 0.f), (float)LF);
    e0 = fminf(fmaxf(e0, s0 + 1e-3f), (float)LF);
    s0 = fmaxf(fminf(s0, e0 - 1e-3f), 0.f);
    bs[t] = s0; be[t] = e0; bsc[t] = score;
    if (score >= 0.1f) atomicOr(&vwords[t >> 6], 1ull << (t & 63));
  }
  __syncthreads();
  // suppression masks: pool[j*10+w] = bits i>j with iou(i,j) > 0.5
  for (int widx = tid; widx < PRE_K * 10; widx += 256) {
    int j = widx / 10;
    int w = widx - j * 10;
    int base = w * 64;
    unsigned long long m = 0ull;
    if (base + 63 > j) {
      float sj = bs[j], ej = be[j];
      float wj = ej - sj;
      for (int bit = 0; bit < 64; ++bit) {
        int i3 = base + bit;
        if (i3 > j && i3 < PRE_K) {
          float inter = fmaxf(fminf(ej, be[i3]) - fmaxf(sj, bs[i3]), 0.f);
          float uni = wj + (be[i3] - bs[i3]) - inter;
          float iou = inter / fmaxf(uni, 1e-6f);
          if (iou > 0.5f) m |= (1ull << bit);
        }
      }
    }
    pool[widx] = m;
  }
  __syncthreads();
  // wave-serial greedy NMS + output (lane w<10 owns removal word w)
  if (wave == 0) {
    unsigned long long rem = 0ull;
    unsigned long long vw = (lane < 10) ? vwords[lane] : 0ull;
    unsigned long long mrow = (lane < 10) ? pool[lane] : 0ull;
    int kept = 0;
    for (int i3 = 0; i3 < PRE_K; ++i3) {
      unsigned long long mnext =
          (lane < 10 && (i3 + 1) < PRE_K) ? pool[(i3 + 1) * 10 + lane] : 0ull;
      unsigned long long avail = vw & ~rem;
      unsigned long long ow = __shfl(avail, i3 >> 6);
      if ((ow >> (i3 & 63)) & 1ull) {
        rem |= mrow;
        if (lane == 0) {
          out[PROPS_OFF + (size_t)b * 200 + 2 * kept]     = bs[i3];
          out[PROPS_OFF + (size_t)b * 200 + 2 * kept + 1] = be[i3];
          out[PSC_OFF + (size_t)b * 100 + kept] = bsc[i3];
          out[PM_OFF  + (size_t)b * 100 + kept] = 1.0f;
        }
        ++kept;
        if (kept >= POST_K) break;
      }
      mrow = mnext;
    }
    if (lane == 0) scal[3] = kept;
  }
  __syncthreads();
  const int kf = scal[3];
  for (int r = tid; r < POST_K; r += 256) {
    if (r >= kf) {
      out[PROPS_OFF + (size_t)b * 200 + 2 * r]     = 0.f;
      out[PROPS_OFF + (size_t)b * 200 + 2 * r + 1] = 0.f;
      out[PSC_OFF + (size_t)b * 100 + r] = 0.f;
      out[PM_OFF  + (size_t)b * 100 + r] = 0.f;
    }
  }
}

extern "C" void kernel_launch(void* const* d_in, const int* in_sizes, int n_in,
                              void* d_out, int out_size, void* d_ws, size_t ws_size,
                              hipStream_t stream) {
  const float* feat = (const float*)d_in[0];
  const float* cw   = (const float*)d_in[1];
  const float* cb   = (const float*)d_in[2];
  const float* ow   = (const float*)d_in[3];
  const float* obb  = (const float*)d_in[4];
  const float* rw   = (const float*)d_in[5];
  const float* rb   = (const float*)d_in[6];
  float* out = (float*)d_out;
  float* wt  = (float*)d_ws;   // 3 MB transposed conv weights

  hipLaunchKernelGGL(transpose_w_k, dim3(3072), dim3(256), 0, stream, cw, wt);
  hipLaunchKernelGGL(anchors_k, dim3(224), dim3(256), 0, stream, out);
  hipLaunchKernelGGL(conv_proj_k, dim3(128, 8), dim3(256), 0, stream,
                     feat, wt, cb, ow, obb, rw, rb, out);
  hipLaunchKernelGGL(propose_k, dim3(8), dim3(256), 0, stream, out);
}

// Round 2
// 2306.946 us; speedup vs baseline: 1.4265x; 1.4265x over previous
//
#include <hip/hip_runtime.h>

#define LF 8192
#define NB 8
#define NC 512
#define NA 7
#define NANCH 57344        // LF*NA
#define PRE_K 600
#define POST_K 100

// output layout (floats), concatenated in reference return order
#define OBJ_OFF   0
#define REG_OFF   458752
#define ANCH_OFF  1376256
#define PROPS_OFF 1490944
#define PSC_OFF   1492544
#define PM_OFF    1493344

// ---------------- weight transpose: conv_w[co][ci][k] -> wt[(ci*3+k)*512+co] ----
__global__ void transpose_w_k(const float* __restrict__ cw, float* __restrict__ wt) {
  int o = blockIdx.x * 256 + threadIdx.x;
  if (o >= 512 * 512 * 3) return;
  int co = o & 511;
  int r  = o >> 9;            // ci*3 + k
  int ci = r / 3;
  int k  = r - ci * 3;
  wt[o] = cw[((size_t)co * 512 + ci) * 3 + k];
}

// ---------------- anchors ------------------------------------------------------
__global__ void anchors_k(float* __restrict__ out) {
  int i = blockIdx.x * 256 + threadIdx.x;
  if (i >= NANCH) return;
  int l = i / 7, a = i - l * 7;
  float len = (float)(a + 1 + (a > 4 ? a - 4 : 0));   // {1,2,3,4,5,7,9}
  float c = (float)l + 0.5f;
  out[ANCH_OFF + 2 * (size_t)i]     = c - 0.5f * len;
  out[ANCH_OFF + 2 * (size_t)i + 1] = c + 0.5f * len;
}

// ---------------- fused conv1d + ReLU + obj/reg projection ---------------------
// lane = c_out, l-tile of 32 in registers. grid (LF/32, B), block 256.
// Thread t owns c_out {t, t+256}; acc0/acc1[32] cover the l-tile.
// Weights: coalesced vector loads (reused over 32 l). Feat: LDS uniform
// broadcast reads. Single pass over ci (feat staged once).
__global__ __launch_bounds__(256, 4) void conv_proj_k(
    const float* __restrict__ feat, const float* __restrict__ wt,
    const float* __restrict__ cbias, const float* __restrict__ obj_w,
    const float* __restrict__ obj_b, const float* __restrict__ reg_w,
    const float* __restrict__ reg_b, float* __restrict__ out)
{
  __shared__ float sf[32][36];      // feat chunk [ci][l0-1 .. l0+32], padded
  __shared__ float bufp[128][36];   // h quarter [co_local][l], padded
  const int tid = threadIdx.x;
  const int l0  = blockIdx.x * 32;
  const int b   = blockIdx.y;
  const int co0 = tid;
  const int co1 = tid + 256;

  float acc0[32], acc1[32];
  {
    float b0 = cbias[co0], b1 = cbias[co1];
    #pragma unroll
    for (int j = 0; j < 32; ++j) { acc0[j] = b0; acc1[j] = b1; }
  }

  const float* fb = feat + ((size_t)b * 512) * LF;

  for (int cb = 0; cb < 512; cb += 32) {
    __syncthreads();
    for (int idx = tid; idx < 32 * 34; idx += 256) {
      int r = idx / 34, c = idx - r * 34;
      int gl = l0 - 1 + c;
      float v = 0.f;
      if (gl >= 0 && gl < LF) v = fb[(size_t)(cb + r) * LF + gl];
      sf[r][c] = v;
    }
    __syncthreads();
    for (int ci = 0; ci < 32; ++ci) {
      const float* wp = wt + (size_t)(cb + ci) * 1536;
      float w00 = wp[co0], w01 = wp[512 + co0], w02 = wp[1024 + co0];
      float w10 = wp[co1], w11 = wp[512 + co1], w12 = wp[1024 + co1];
      const float4* fr = (const float4*)&sf[ci][0];   // wave-uniform -> broadcast
      float4 cur = fr[0];
      #pragma unroll
      for (int g = 0; g < 8; ++g) {
        float4 nxt = fr[g + 1];
        int l = 4 * g;
        acc0[l]     = fmaf(w00, cur.x, fmaf(w01, cur.y, fmaf(w02, cur.z, acc0[l])));
        acc1[l]     = fmaf(w10, cur.x, fmaf(w11, cur.y, fmaf(w12, cur.z, acc1[l])));
        acc0[l + 1] = fmaf(w00, cur.y, fmaf(w01, cur.z, fmaf(w02, cur.w, acc0[l + 1])));
        acc1[l + 1] = fmaf(w10, cur.y, fmaf(w11, cur.z, fmaf(w12, cur.w, acc1[l + 1])));
        acc0[l + 2] = fmaf(w00, cur.z, fmaf(w01, cur.w, fmaf(w02, nxt.x, acc0[l + 2])));
        acc1[l + 2] = fmaf(w10, cur.z, fmaf(w11, cur.w, fmaf(w12, nxt.x, acc1[l + 2])));
        acc0[l + 3] = fmaf(w00, cur.w, fmaf(w01, nxt.x, fmaf(w02, nxt.y, acc0[l + 3])));
        acc1[l + 3] = fmaf(w10, cur.w, fmaf(w11, nxt.x, fmaf(w12, nxt.y, acc1[l + 3])));
        cur = nxt;
      }
    }
  }

  // ---- projection epilogue: route h through LDS in 128-co quarters ----
  const int sg = tid >> 5;          // subgroup 0..7: rows r = 3*sg + q
  const int ll = tid & 31;          // l within tile
  const int r0 = sg * 3;
  auto row_ptr = [&](int r) -> const float* {
    int rc = r < 21 ? r : 20;       // clamp (sg==7 rows unused)
    return (rc < 7) ? (obj_w + (size_t)rc * 512) : (reg_w + (size_t)(rc - 7) * 512);
  };
  const float* wr0 = row_ptr(r0);
  const float* wr1 = row_ptr(r0 + 1);
  const float* wr2 = row_ptr(r0 + 2);
  float pacc[3] = {0.f, 0.f, 0.f};

  auto dump = [&](float (&a)[32], int cl) {
    #pragma unroll
    for (int g = 0; g < 8; ++g) {
      float4 v;
      v.x = fmaxf(a[4 * g], 0.f);
      v.y = fmaxf(a[4 * g + 1], 0.f);
      v.z = fmaxf(a[4 * g + 2], 0.f);
      v.w = fmaxf(a[4 * g + 3], 0.f);
      *(float4*)&bufp[cl][4 * g] = v;
    }
  };

  #pragma unroll
  for (int qh = 0; qh < 4; ++qh) {
    __syncthreads();
    if (qh == 0)      { if (tid < 128)  dump(acc0, tid); }
    else if (qh == 1) { if (tid >= 128) dump(acc0, tid - 128); }
    else if (qh == 2) { if (tid < 128)  dump(acc1, tid); }
    else              { if (tid >= 128) dump(acc1, tid - 128); }
    __syncthreads();
    const float* w0p = wr0 + qh * 128;
    const float* w1p = wr1 + qh * 128;
    const float* w2p = wr2 + qh * 128;
    for (int c4 = 0; c4 < 32; ++c4) {
      float4 wa = *(const float4*)(w0p + 4 * c4);
      float4 wb = *(const float4*)(w1p + 4 * c4);
      float4 wc = *(const float4*)(w2p + 4 * c4);
      float h0 = bufp[4 * c4 + 0][ll];
      float h1 = bufp[4 * c4 + 1][ll];
      float h2 = bufp[4 * c4 + 2][ll];
      float h3 = bufp[4 * c4 + 3][ll];
      pacc[0] = fmaf(wa.x, h0, fmaf(wa.y, h1, fmaf(wa.z, h2, fmaf(wa.w, h3, pacc[0]))));
      pacc[1] = fmaf(wb.x, h0, fmaf(wb.y, h1, fmaf(wb.z, h2, fmaf(wb.w, h3, pacc[1]))));
      pacc[2] = fmaf(wc.x, h0, fmaf(wc.y, h1, fmaf(wc.z, h2, fmaf(wc.w, h3, pacc[2]))));
    }
  }

  const size_t ob = (size_t)b * NANCH;
  const int l = l0 + ll;
  #pragma unroll
  for (int q = 0; q < 3; ++q) {
    int r = r0 + q;
    if (r < 21) {
      float v = pacc[q] + ((r < 7) ? obj_b[r] : reg_b[r - 7]);
      if (r < 7) {
        out[OBJ_OFF + ob + (size_t)l * 7 + r] = v;
      } else {
        int rr = r - 7;
        out[REG_OFF + (ob + (size_t)l * 7 + (rr >> 1)) * 2 + (rr & 1)] = v;
      }
    }
  }
}

// ---------------- helper: locate bin containing rank-K from top ----------------
__device__ __forceinline__ void find_bin(unsigned* hist, unsigned* coarse,
                                         int K, int tid, int* res) {
  unsigned s4 = hist[4 * tid] + hist[4 * tid + 1] + hist[4 * tid + 2] + hist[4 * tid + 3];
  coarse[tid] = s4;
  __syncthreads();
  for (int off = 1; off < 256; off <<= 1) {
    unsigned v = coarse[tid];
    unsigned add = (tid + off < 256) ? coarse[tid + off] : 0u;
    __syncthreads();
    coarse[tid] = v + add;
    __syncthreads();
  }
  unsigned sfx  = coarse[tid];
  unsigned sfx1 = (tid < 255) ? coarse[tid + 1] : 0u;
  if (sfx >= (unsigned)K && sfx1 < (unsigned)K) {
    unsigned above = sfx1;
    int bin = 4 * tid;
    for (int bb = 4 * tid + 3; bb >= 4 * tid; --bb) {
      unsigned c = hist[bb];
      if (above + c >= (unsigned)K) { bin = bb; break; }
      above += c;
    }
    res[0] = bin;
    res[1] = (int)above;
  }
  __syncthreads();
}

// ---------------- per-batch top-600 -> NMS -> top-100 --------------------------
__global__ __launch_bounds__(256) void propose_k(float* __restrict__ out) {
  const int b = blockIdx.x;
  const int tid = threadIdx.x;
  const int lane = tid & 63;
  const int wave = tid >> 6;

  __shared__ unsigned long long pool[PRE_K * 10];  // 48 KB; first 1024 = sort keys
  __shared__ unsigned int hist[1024];
  __shared__ unsigned int coarse[256];
  __shared__ float bs[PRE_K], be[PRE_K], bsc[PRE_K];
  __shared__ unsigned long long vwords[10];
  __shared__ int scal[4];   // 0: bin, 1: before, 2: cand cnt, 3: kept

  unsigned long long* keys = pool;
  const float* obj = out + OBJ_OFF + (size_t)b * NANCH;

  for (int i = tid; i < 1024; i += 256) hist[i] = 0u;
  if (tid < 10) vwords[tid] = 0ull;
  if (tid == 0) scal[2] = 0;
  __syncthreads();

  // pass 1: histogram on score bits [31:22] (scores positive -> bit order = value order)
  for (int i = tid; i < NANCH; i += 256) {
    float s = 1.f / (1.f + expf(-obj[i]));
    unsigned u = __float_as_uint(s);
    atomicAdd(&hist[u >> 22], 1u);
  }
  __syncthreads();
  find_bin(hist, coarse, PRE_K, tid, scal);
  const int b1 = scal[0];
  const int before = scal[1];
  __syncthreads();
  for (int i = tid; i < 1024; i += 256) hist[i] = 0u;
  __syncthreads();
  // pass 2: refine next 10 bits within bin b1
  for (int i = tid; i < NANCH; i += 256) {
    float s = 1.f / (1.f + expf(-obj[i]));
    unsigned u = __float_as_uint(s);
    if ((int)(u >> 22) == b1) atomicAdd(&hist[(u >> 12) & 1023u], 1u);
  }
  __syncthreads();
  find_bin(hist, coarse, PRE_K - before, tid, scal);
  const unsigned Tbits = ((unsigned)b1 << 22) | ((unsigned)scal[0] << 12);
  __syncthreads();
  // gather candidates (>=600 guaranteed, ~600 expected)
  for (int i = tid; i < NANCH; i += 256) {
    float s = 1.f / (1.f + expf(-obj[i]));
    unsigned u = __float_as_uint(s);
    if (u >= Tbits) {
      int p = atomicAdd(&scal[2], 1);
      if (p < 1024)
        keys[p] = ((unsigned long long)u << 32) | (unsigned long long)(~(unsigned)i);
    }
  }
  __syncthreads();
  const int cnt = scal[2];
  for (int p = tid; p < 1024; p += 256) if (p >= cnt) keys[p] = 0ull;
  // bitonic sort descending (key: score bits major, ~idx minor -> ties by lower idx)
  for (unsigned k = 2; k <= 1024; k <<= 1) {
    for (unsigned j = k >> 1; j > 0; j >>= 1) {
      __syncthreads();
      for (unsigned idx = tid; idx < 1024; idx += 256) {
        unsigned partner = idx ^ j;
        if (partner > idx) {
          unsigned long long a = keys[idx], c = keys[partner];
          bool up = ((idx & k) == 0);
          if (up ? (a < c) : (a > c)) { keys[idx] = c; keys[partner] = a; }
        }
      }
    }
  }
  __syncthreads();
  // decode top-600 boxes
  for (int t = tid; t < PRE_K; t += 256) {
    unsigned long long kv = keys[t];
    unsigned u  = (unsigned)(kv >> 32);
    unsigned i2 = ~((unsigned)kv);
    float score = __uint_as_float(u);
    int li = (int)(i2 / 7u);
    int a  = (int)(i2 - (unsigned)li * 7u);
    float alen = (float)(a + 1 + (a > 4 ? a - 4 : 0));
    const float* rp = out + REG_OFF + ((size_t)b * NANCH + i2) * 2;
    float tc = rp[0];
    float tw = fminf(fmaxf(rp[1], -10.f), 10.f);
    float cc = (float)li + 0.5f + tc * alen;
    float ww = alen * expf(tw);
    float s0 = cc - 0.5f * ww;
    float e0 = cc + 0.5f * ww;
    s0 = fminf(fmaxf(s0, 0.f), (float)LF);
    e0 = fminf(fmaxf(e0, 0.f), (float)LF);
    e0 = fminf(fmaxf(e0, s0 + 1e-3f), (float)LF);
    s0 = fmaxf(fminf(s0, e0 - 1e-3f), 0.f);
    bs[t] = s0; be[t] = e0; bsc[t] = score;
    if (score >= 0.1f) atomicOr(&vwords[t >> 6], 1ull << (t & 63));
  }
  __syncthreads();
  // suppression masks: pool[j*10+w] = bits i>j with iou(i,j) > 0.5
  for (int widx = tid; widx < PRE_K * 10; widx += 256) {
    int j = widx / 10;
    int w = widx - j * 10;
    int base = w * 64;
    unsigned long long m = 0ull;
    if (base + 63 > j) {
      float sj = bs[j], ej = be[j];
      float wj = ej - sj;
      for (int bit = 0; bit < 64; ++bit) {
        int i3 = base + bit;
        if (i3 > j && i3 < PRE_K) {
          float inter = fmaxf(fminf(ej, be[i3]) - fmaxf(sj, bs[i3]), 0.f);
          float uni = wj + (be[i3] - bs[i3]) - inter;
          float iou = inter / fmaxf(uni, 1e-6f);
          if (iou > 0.5f) m |= (1ull << bit);
        }
      }
    }
    pool[widx] = m;
  }
  __syncthreads();
  // wave-serial greedy NMS + output (lane w<10 owns removal word w)
  if (wave == 0) {
    unsigned long long rem = 0ull;
    unsigned long long vw = (lane < 10) ? vwords[lane] : 0ull;
    unsigned long long mrow = (lane < 10) ? pool[lane] : 0ull;
    int kept = 0;
    for (int i3 = 0; i3 < PRE_K; ++i3) {
      unsigned long long mnext =
          (lane < 10 && (i3 + 1) < PRE_K) ? pool[(i3 + 1) * 10 + lane] : 0ull;
      unsigned long long avail = vw & ~rem;
      unsigned long long ow = __shfl(avail, i3 >> 6);
      if ((ow >> (i3 & 63)) & 1ull) {
        rem |= mrow;
        if (lane == 0) {
          out[PROPS_OFF + (size_t)b * 200 + 2 * kept]     = bs[i3];
          out[PROPS_OFF + (size_t)b * 200 + 2 * kept + 1] = be[i3];
          out[PSC_OFF + (size_t)b * 100 + kept] = bsc[i3];
          out[PM_OFF  + (size_t)b * 100 + kept] = 1.0f;
        }
        ++kept;
        if (kept >= POST_K) break;
      }
      mrow = mnext;
    }
    if (lane == 0) scal[3] = kept;
  }
  __syncthreads();
  const int kf = scal[3];
  for (int r = tid; r < POST_K; r += 256) {
    if (r >= kf) {
      out[PROPS_OFF + (size_t)b * 200 + 2 * r]     = 0.f;
      out[PROPS_OFF + (size_t)b * 200 + 2 * r + 1] = 0.f;
      out[PSC_OFF + (size_t)b * 100 + r] = 0.f;
      out[PM_OFF  + (size_t)b * 100 + r] = 0.f;
    }
  }
}

extern "C" void kernel_launch(void* const* d_in, const int* in_sizes, int n_in,
                              void* d_out, int out_size, void* d_ws, size_t ws_size,
                              hipStream_t stream) {
  const float* feat = (const float*)d_in[0];
  const float* cw   = (const float*)d_in[1];
  const float* cb   = (const float*)d_in[2];
  const float* ow   = (const float*)d_in[3];
  const float* obb  = (const float*)d_in[4];
  const float* rw   = (const float*)d_in[5];
  const float* rb   = (const float*)d_in[6];
  float* out = (float*)d_out;
  float* wt  = (float*)d_ws;   // 3 MB transposed conv weights

  hipLaunchKernelGGL(transpose_w_k, dim3(3072), dim3(256), 0, stream, cw, wt);
  hipLaunchKernelGGL(anchors_k, dim3(224), dim3(256), 0, stream, out);
  hipLaunchKernelGGL(conv_proj_k, dim3(256, 8), dim3(256), 0, stream,
                     feat, wt, cb, ow, obb, rw, rb, out);
  hipLaunchKernelGGL(propose_k, dim3(8), dim3(256), 0, stream, out);
}